// Round 12
// baseline (399.576 us; speedup 1.0000x reference)
//
#include <hip/hip_runtime.h>

static constexpr int Dd = 128;   // feature dim
static constexpr int Hh = 64;    // MLP hidden
static constexpr int OC = 10;    // output classes
#define CDIV(a,b) (((a)+(b)-1)/(b))

typedef __attribute__((ext_vector_type(8))) short short8v;
typedef __attribute__((ext_vector_type(16))) float f32x16;
typedef unsigned short u16;

__device__ __forceinline__ float lrelu(float x){ return x>0.f? x : 0.2f*x; }
__device__ __forceinline__ unsigned f2bf(float f){
  unsigned u = __float_as_uint(f);
  return (u + 0x7FFFu + ((u>>16)&1u)) >> 16;
}
__device__ __forceinline__ float bl(unsigned u){ return __uint_as_float(u<<16); }
__device__ __forceinline__ float bh(unsigned u){ return __uint_as_float(u & 0xFFFF0000u); }

// ======================= CSR build =======================
__global__ __launch_bounds__(256) void k_hist(const int* __restrict__ dst, int E,
    int* __restrict__ cnt) {
  int e = blockIdx.x*256 + threadIdx.x;
  if (e < E) atomicAdd(cnt + dst[e], 1);
}

__global__ __launch_bounds__(256) void k_scan_l1(const int* __restrict__ cnt,
    int* __restrict__ rp, int n, int* __restrict__ bsum) {
  __shared__ int sdata[256];
  int t = threadIdx.x;
  int base = blockIdx.x*2048 + t*8;
  int v[8]; int s = 0;
  #pragma unroll
  for (int k = 0; k < 8; k++) { v[k] = (base+k < n) ? cnt[base+k] : 0; s += v[k]; }
  sdata[t] = s; __syncthreads();
  for (int off = 1; off < 256; off <<= 1) {
    int a = sdata[t];
    int b = (t >= off) ? sdata[t-off] : 0;
    __syncthreads();
    sdata[t] = a + b;
    __syncthreads();
  }
  int ex = sdata[t] - s;
  if (t == 255) bsum[blockIdx.x] = sdata[255];
  int run = ex;
  #pragma unroll
  for (int k = 0; k < 8; k++) { if (base+k < n) rp[base+k] = run; run += v[k]; }
}

__global__ void k_scan_l2(int* __restrict__ bsum, int nb) {
  if (threadIdx.x == 0 && blockIdx.x == 0) {
    int run = 0;
    for (int i = 0; i < nb; i++) { int v = bsum[i]; bsum[i] = run; run += v; }
  }
}

__global__ __launch_bounds__(256) void k_scan_l3(int* __restrict__ rp, int n,
    const int* __restrict__ bsum, int E) {
  int off = bsum[blockIdx.x];
  int base = blockIdx.x*2048 + threadIdx.x*8;
  #pragma unroll
  for (int k = 0; k < 8; k++) if (base+k < n) rp[base+k] += off;
  if (blockIdx.x == 0 && threadIdx.x == 0) rp[n] = E;
}

__global__ __launch_bounds__(256) void k_fill(const int* __restrict__ src,
    const int* __restrict__ dst, int E, const int* __restrict__ rp,
    int* __restrict__ cnt, int* __restrict__ col) {
  int e = blockIdx.x*256 + threadIdx.x;
  if (e >= E) return;
  int d = dst[e];
  int pos = rp[d] + atomicSub(cnt + d, 1) - 1;
  col[pos] = src[e];
}

__global__ __launch_bounds__(256) void k_dinv(const int* __restrict__ rp,
    float* __restrict__ dinv, int n) {
  int i = blockIdx.x*256 + threadIdx.x;
  if (i < n) dinv[i] = rsqrtf((float)(rp[i+1] - rp[i]) + 1.0f);
}

// ======================= weight prep: 32x32-MFMA fragment order =======================
// kc=k>>3 (16 chunks), nf=n>>5, lm=n&31: fi = ((kc*(N/32)+nf)*32+lm)*8 + (k&7)
// -> each (kc,nf) slab is 512B contiguous; compute-loop read = 512B-contiguous
//    per 32-lane half (fully coalesced, L1-resident 32KB).
__global__ __launch_bounds__(256) void k_wt_all(
    const float* __restrict__ w0, const float* __restrict__ w1,
    const float* __restrict__ w2, const float* __restrict__ w3,
    const float* __restrict__ w4,
    u16* __restrict__ o0, u16* __restrict__ o1, u16* __restrict__ o2,
    u16* __restrict__ o3, u16* __restrict__ o4) {
  int idx = blockIdx.x*256 + threadIdx.x;
  const float* W; u16* O; int base, N;
  if (idx < 65536) {
    int m = idx >> 14;
    W = m==0?w0 : m==1?w1 : m==2?w2 : w3;
    O = m==0?o0 : m==1?o1 : m==2?o2 : o3;
    base = idx & 16383; N = 128;
  } else if (idx < 73728) {
    W = w4; O = o4; base = idx - 65536; N = 64;
  } else return;
  int n = base / 128, k = base % 128;
  int kc = k >> 3, nf = n >> 5, lm = n & 31;
  int fi = (((kc*(N>>5) + nf)*32 + lm) << 3) | (k & 7);
  O[fi] = (u16)f2bf(W[k*N + n]);
}

// ======================= x -> bf16 =======================
__global__ __launch_bounds__(256) void k_tobf16(const float* __restrict__ in,
    u16* __restrict__ out, int n8) {
  int idx = blockIdx.x*256 + threadIdx.x;
  if (idx >= n8) return;
  const float4* p = reinterpret_cast<const float4*>(in) + idx*2;
  float4 v0 = p[0], v1 = p[1];
  uint4 w;
  w.x = f2bf(v0.x) | (f2bf(v0.y)<<16);
  w.y = f2bf(v0.z) | (f2bf(v0.w)<<16);
  w.z = f2bf(v1.x) | (f2bf(v1.y)<<16);
  w.w = f2bf(v1.z) | (f2bf(v1.w)<<16);
  reinterpret_cast<uint4*>(out)[idx] = w;
}

// ======================= gathers: 32 lanes/node, bf16 rows, unroll x4 =======================
__global__ __launch_bounds__(256) void k_sage_gather(const u16* __restrict__ xb,
    const int* __restrict__ rp, const int* __restrict__ col,
    u16* __restrict__ ob, int n) {
  int gid = blockIdx.x*256 + threadIdx.x;
  int i = gid >> 5, l = gid & 31;
  if (i >= n) return;
  int beg = rp[i], end = rp[i+1];
  const u16* xp = xb + l*4;
  float a0=0.f, a1=0.f, a2=0.f, a3=0.f;
  int j = beg;
  for (; j+4 <= end; j += 4) {
    int s0=col[j], s1=col[j+1], s2=col[j+2], s3=col[j+3];
    uint2 v0 = *reinterpret_cast<const uint2*>(xp + (size_t)s0*Dd);
    uint2 v1 = *reinterpret_cast<const uint2*>(xp + (size_t)s1*Dd);
    uint2 v2 = *reinterpret_cast<const uint2*>(xp + (size_t)s2*Dd);
    uint2 v3 = *reinterpret_cast<const uint2*>(xp + (size_t)s3*Dd);
    a0 += (bl(v0.x)+bl(v1.x)) + (bl(v2.x)+bl(v3.x));
    a1 += (bh(v0.x)+bh(v1.x)) + (bh(v2.x)+bh(v3.x));
    a2 += (bl(v0.y)+bl(v1.y)) + (bl(v2.y)+bl(v3.y));
    a3 += (bh(v0.y)+bh(v1.y)) + (bh(v2.y)+bh(v3.y));
  }
  for (; j < end; j++) {
    int s = col[j];
    uint2 v = *reinterpret_cast<const uint2*>(xp + (size_t)s*Dd);
    a0 += bl(v.x); a1 += bh(v.x); a2 += bl(v.y); a3 += bh(v.y);
  }
  float inv = 1.0f / fmaxf((float)(end - beg), 1.0f);
  uint2 o;
  o.x = f2bf(a0*inv) | (f2bf(a1*inv)<<16);
  o.y = f2bf(a2*inv) | (f2bf(a3*inv)<<16);
  *reinterpret_cast<uint2*>(ob + (size_t)i*Dd + l*4) = o;
}

__global__ __launch_bounds__(256) void k_gcn_gather(const u16* __restrict__ xb,
    const int* __restrict__ rp, const int* __restrict__ col,
    const float* __restrict__ dinv, u16* __restrict__ ob, int n) {
  int gid = blockIdx.x*256 + threadIdx.x;
  int i = gid >> 5, l = gid & 31;
  if (i >= n) return;
  int beg = rp[i], end = rp[i+1];
  const u16* xp = xb + l*4;
  float a0=0.f, a1=0.f, a2=0.f, a3=0.f;
  int j = beg;
  for (; j+4 <= end; j += 4) {
    int s0=col[j], s1=col[j+1], s2=col[j+2], s3=col[j+3];
    uint2 v0 = *reinterpret_cast<const uint2*>(xp + (size_t)s0*Dd);
    uint2 v1 = *reinterpret_cast<const uint2*>(xp + (size_t)s1*Dd);
    uint2 v2 = *reinterpret_cast<const uint2*>(xp + (size_t)s2*Dd);
    uint2 v3 = *reinterpret_cast<const uint2*>(xp + (size_t)s3*Dd);
    float w0 = dinv[s0], w1 = dinv[s1], w2 = dinv[s2], w3 = dinv[s3];
    a0 += (w0*bl(v0.x)+w1*bl(v1.x)) + (w2*bl(v2.x)+w3*bl(v3.x));
    a1 += (w0*bh(v0.x)+w1*bh(v1.x)) + (w2*bh(v2.x)+w3*bh(v3.x));
    a2 += (w0*bl(v0.y)+w1*bl(v1.y)) + (w2*bl(v2.y)+w3*bl(v3.y));
    a3 += (w0*bh(v0.y)+w1*bh(v1.y)) + (w2*bh(v2.y)+w3*bh(v3.y));
  }
  for (; j < end; j++) {
    int s = col[j];
    float w = dinv[s];
    uint2 v = *reinterpret_cast<const uint2*>(xp + (size_t)s*Dd);
    a0 += w*bl(v.x); a1 += w*bh(v.x); a2 += w*bl(v.y); a3 += w*bh(v.y);
  }
  float di = dinv[i];
  float ws = di*di;
  uint2 sv = *reinterpret_cast<const uint2*>(xp + (size_t)i*Dd);
  a0 = di*a0 + ws*bl(sv.x); a1 = di*a1 + ws*bh(sv.x);
  a2 = di*a2 + ws*bl(sv.y); a3 = di*a3 + ws*bh(sv.y);
  uint2 o;
  o.x = f2bf(a0) | (f2bf(a1)<<16);
  o.y = f2bf(a2) | (f2bf(a3)<<16);
  *reinterpret_cast<uint2*>(ob + (size_t)i*Dd + l*4) = o;
}

// single-pass online-softmax GAT gather
__global__ __launch_bounds__(256) void k_gat_gather(const u16* __restrict__ xb,
    const int* __restrict__ rp, const int* __restrict__ col,
    const float* __restrict__ a_s, const float* __restrict__ a_d,
    u16* __restrict__ ob, int n) {
  int gid = blockIdx.x*256 + threadIdx.x;
  int i = gid >> 5, l = gid & 31;
  if (i >= n) return;
  int beg = rp[i], end = rp[i+1];
  const u16* xp = xb + l*4;
  float ad = a_d[i];
  float m = lrelu(a_s[i] + ad);
  float z = 1.0f;
  uint2 sv = *reinterpret_cast<const uint2*>(xp + (size_t)i*Dd);
  float a0 = bl(sv.x), a1 = bh(sv.x), a2 = bl(sv.y), a3 = bh(sv.y);
  int j = beg;
  for (; j+4 <= end; j += 4) {
    int s0=col[j], s1=col[j+1], s2=col[j+2], s3=col[j+3];
    uint2 v0 = *reinterpret_cast<const uint2*>(xp + (size_t)s0*Dd);
    uint2 v1 = *reinterpret_cast<const uint2*>(xp + (size_t)s1*Dd);
    uint2 v2 = *reinterpret_cast<const uint2*>(xp + (size_t)s2*Dd);
    uint2 v3 = *reinterpret_cast<const uint2*>(xp + (size_t)s3*Dd);
    float e0 = lrelu(a_s[s0]+ad), e1 = lrelu(a_s[s1]+ad);
    float e2 = lrelu(a_s[s2]+ad), e3 = lrelu(a_s[s3]+ad);
    float mg = fmaxf(fmaxf(e0,e1), fmaxf(e2,e3));
    if (mg > m) {
      float r = __expf(m - mg);
      z *= r; a0 *= r; a1 *= r; a2 *= r; a3 *= r;
      m = mg;
    }
    float w0 = __expf(e0-m), w1 = __expf(e1-m);
    float w2 = __expf(e2-m), w3 = __expf(e3-m);
    z += (w0+w1) + (w2+w3);
    a0 += (w0*bl(v0.x)+w1*bl(v1.x)) + (w2*bl(v2.x)+w3*bl(v3.x));
    a1 += (w0*bh(v0.x)+w1*bh(v1.x)) + (w2*bh(v2.x)+w3*bh(v3.x));
    a2 += (w0*bl(v0.y)+w1*bl(v1.y)) + (w2*bl(v2.y)+w3*bl(v3.y));
    a3 += (w0*bh(v0.y)+w1*bh(v1.y)) + (w2*bh(v2.y)+w3*bh(v3.y));
  }
  for (; j < end; j++) {
    int s = col[j];
    uint2 v = *reinterpret_cast<const uint2*>(xp + (size_t)s*Dd);
    float e = lrelu(a_s[s]+ad);
    if (e > m) {
      float r = __expf(m - e);
      z *= r; a0 *= r; a1 *= r; a2 *= r; a3 *= r;
      m = e;
    }
    float w = __expf(e-m);
    z += w;
    a0 += w*bl(v.x); a1 += w*bh(v.x); a2 += w*bl(v.y); a3 += w*bh(v.y);
  }
  float inv = 1.0f / z;
  uint2 o;
  o.x = f2bf(a0*inv) | (f2bf(a1*inv)<<16);
  o.y = f2bf(a2*inv) | (f2bf(a3*inv)<<16);
  *reinterpret_cast<uint2*>(ob + (size_t)i*Dd + l*4) = o;
}

// ======================= BN stats over bf16 buffer =======================
__global__ __launch_bounds__(256) void k_bn_stats_bf(const u16* __restrict__ X, int M,
    float* __restrict__ gsum, float* __restrict__ gsq) {
  __shared__ float ss[2][256];
  int t = threadIdx.x;
  int cd = t & 63;
  int rg = t >> 6;
  float s0=0.f, q0=0.f, s1=0.f, q1=0.f;
  const unsigned* Xu = reinterpret_cast<const unsigned*>(X);
  for (int r = blockIdx.x*4 + rg; r < M; r += gridDim.x*4) {
    unsigned v = Xu[(size_t)r*64 + cd];
    float a = bl(v), b = bh(v);
    s0 += a; q0 += a*a; s1 += b; q1 += b*b;
  }
  ss[0][t] = s0; ss[1][t] = q0; __syncthreads();
  float rs0 = 0.f, rq0 = 0.f;
  if (rg == 0) {
    rs0 = ss[0][cd] + ss[0][cd+64] + ss[0][cd+128] + ss[0][cd+192];
    rq0 = ss[1][cd] + ss[1][cd+64] + ss[1][cd+128] + ss[1][cd+192];
  }
  __syncthreads();
  ss[0][t] = s1; ss[1][t] = q1; __syncthreads();
  if (rg == 0) {
    float rs1 = ss[0][cd] + ss[0][cd+64] + ss[0][cd+128] + ss[0][cd+192];
    float rq1 = ss[1][cd] + ss[1][cd+64] + ss[1][cd+128] + ss[1][cd+192];
    atomicAdd(gsum + 2*cd,     rs0); atomicAdd(gsq + 2*cd,     rq0);
    atomicAdd(gsum + 2*cd + 1, rs1); atomicAdd(gsq + 2*cd + 1, rq1);
  }
}

// ======================= MFMA GEMM v5: A padded-LDS, W direct-from-global =======================
// 128 rows/block, 4 waves, 32x32x16. A staged to padded LDS [128][136]u16
// (row stride 272B -> conflict-free fragment reads). W read straight from
// fragment-order global (32KB, L1-resident, 512B-contiguous per half-wave).
// LDS ~= 35KB -> 4 blocks/CU (was 68.6KB -> 1-2). HEAD: fused lin2+log_softmax.
template<int NCOLS, bool DUAL, bool BNA, bool STATS, bool BIASRELU, bool ATT, bool OUTBF, bool HEAD>
__global__ __launch_bounds__(256) void k_mm(
    const u16* __restrict__ A1, const u16* __restrict__ A2,
    const u16* __restrict__ WT1, const u16* __restrict__ WT2,
    const float* __restrict__ bng, const float* __restrict__ bnb,
    const float* __restrict__ bsum_in, const float* __restrict__ bsq_in,
    const float* __restrict__ bias,
    void* __restrict__ Cout, int M,
    float* __restrict__ gsum, float* __restrict__ gsq,
    const float* __restrict__ att_sv, const float* __restrict__ att_dv,
    float* __restrict__ as_out, float* __restrict__ ad_out,
    const float* __restrict__ W2, const float* __restrict__ b2) {
  constexpr int NF = NCOLS/32;                 // 4 or 2
  __shared__ char ldsA[128*272];               // 34.8KB padded A (m1 scratch in HEAD)
  __shared__ float s_scale[128], s_shift[128];
  __shared__ float s_sum[128], s_sq[128];
  __shared__ float w2s[Hh][OC];
  __shared__ float b2s[OC];
  int t = threadIdx.x;
  int wave = t >> 6, l = t & 63;
  int lm = l & 31, h = l >> 5;
  int row0 = blockIdx.x*128;

  if constexpr (BNA) {
    if (t < 128) {
      float mu = bsum_in[t] / (float)M;
      float var = fmaxf(bsq_in[t] / (float)M - mu*mu, 0.f);
      float sc = bng[t] * rsqrtf(var + 1e-5f);
      s_scale[t] = sc;
      s_shift[t] = bnb[t] - mu*sc;
    }
  }
  if constexpr (STATS) {
    if (t < 128) { s_sum[t] = 0.f; s_sq[t] = 0.f; }
  }
  if constexpr (HEAD) {
    for (int i = t; i < Hh*OC; i += 256) w2s[i/OC][i%OC] = W2[i];
    if (t < OC) b2s[t] = b2[t];
  }
  if (BNA || STATS || HEAD) __syncthreads();

  f32x16 acc[NF];
  #pragma unroll
  for (int nf = 0; nf < NF; nf++)
    #pragma unroll
    for (int i = 0; i < 16; i++) acc[nf][i] = 0.f;

  const int nph = DUAL ? 2 : 1;
  for (int ph = 0; ph < nph; ph++) {
    if (ph) __syncthreads();
    const u16* A = (DUAL && ph) ? A2 : A1;
    const u16* WT = (DUAL && ph) ? WT2 : WT1;
    // ---- stage A: 2048 16B-chunks; global read fully coalesced; padded LDS ----
    #pragma unroll
    for (int i = 0; i < 8; i++) {
      int c = i*256 + t; int row = c >> 4; int k0 = (c & 15) << 3;
      uint4 w = {0,0,0,0};
      if (row0 + row < M)
        w = *reinterpret_cast<const uint4*>(A + (size_t)(row0+row)*128 + k0);
      if constexpr (BNA) {
        float4 sc0 = *reinterpret_cast<const float4*>(&s_scale[k0]);
        float4 sc1 = *reinterpret_cast<const float4*>(&s_scale[k0+4]);
        float4 sh0 = *reinterpret_cast<const float4*>(&s_shift[k0]);
        float4 sh1 = *reinterpret_cast<const float4*>(&s_shift[k0+4]);
        float e0 = fmaxf(bl(w.x)*sc0.x+sh0.x, 0.f), e1 = fmaxf(bh(w.x)*sc0.y+sh0.y, 0.f);
        float e2 = fmaxf(bl(w.y)*sc0.z+sh0.z, 0.f), e3 = fmaxf(bh(w.y)*sc0.w+sh0.w, 0.f);
        float e4 = fmaxf(bl(w.z)*sc1.x+sh1.x, 0.f), e5 = fmaxf(bh(w.z)*sc1.y+sh1.y, 0.f);
        float e6 = fmaxf(bl(w.w)*sc1.z+sh1.z, 0.f), e7 = fmaxf(bh(w.w)*sc1.w+sh1.w, 0.f);
        w.x = f2bf(e0) | (f2bf(e1)<<16);
        w.y = f2bf(e2) | (f2bf(e3)<<16);
        w.z = f2bf(e4) | (f2bf(e5)<<16);
        w.w = f2bf(e6) | (f2bf(e7)<<16);
      }
      *reinterpret_cast<uint4*>(ldsA + row*272 + k0*2) = w;
    }
    __syncthreads();
    // ---- compute: 8 k-steps; W direct from global (frag order, L1-hot) ----
    const short8v* wp = reinterpret_cast<const short8v*>(WT);
    #pragma unroll
    for (int ks = 0; ks < 8; ks++) {
      int kc = ks*2 + h;                       // 16B chunk index
      int arow = wave*32 + lm;
      short8v af = *reinterpret_cast<short8v*>(ldsA + arow*272 + kc*16);
      #pragma unroll
      for (int nf = 0; nf < NF; nf++) {
        short8v bf = wp[(kc*NF + nf)*32 + lm];
        acc[nf] = __builtin_amdgcn_mfma_f32_32x32x16_bf16(af, bf, acc[nf], 0, 0, 0);
      }
    }
  }
  // ---- epilogue ----
  if constexpr (HEAD) {
    __syncthreads();                           // A reads done; reuse ldsA for m1
    float* mrow = reinterpret_cast<float*>(ldsA);  // [128][65]
    #pragma unroll
    for (int nf = 0; nf < NF; nf++) {
      int colg = nf*32 + lm;
      float bv = bias[colg];
      #pragma unroll
      for (int reg = 0; reg < 16; reg++) {
        int row = wave*32 + (reg&3) + 8*(reg>>2) + 4*h;
        mrow[row*65 + colg] = fmaxf(acc[nf][reg] + bv, 0.f);
      }
    }
    __syncthreads();
    if (t < 128) {
      int row = row0 + t;
      if (row < M) {
        float p[OC];
        #pragma unroll
        for (int c = 0; c < OC; c++) p[c] = b2s[c];
        for (int k = 0; k < Hh; k++) {
          float a = mrow[t*65 + k];
          #pragma unroll
          for (int c = 0; c < OC; c++) p[c] += a * w2s[k][c];
        }
        float mx = p[0];
        #pragma unroll
        for (int c = 1; c < OC; c++) mx = fmaxf(mx, p[c]);
        float s = 0.f;
        #pragma unroll
        for (int c = 0; c < OC; c++) s += __expf(p[c] - mx);
        float lse = mx + __logf(s);
        #pragma unroll
        for (int c = 0; c < OC; c++)
          ((float*)Cout)[(size_t)row*OC + c] = p[c] - lse;
      }
    }
    return;
  }
  #pragma unroll
  for (int nf = 0; nf < NF; nf++) {
    int colg = nf*32 + lm;
    float bv = 0.f;
    if constexpr (BIASRELU) bv = bias[colg];
    float ps = 0.f, pq = 0.f;
    #pragma unroll
    for (int reg = 0; reg < 16; reg++) {
      int row = row0 + wave*32 + (reg&3) + 8*(reg>>2) + 4*h;
      float v = acc[nf][reg];
      if constexpr (BIASRELU) v = fmaxf(v + bv, 0.f);
      if (row < M) {
        if constexpr (OUTBF)
          ((u16*)Cout)[(size_t)row*NCOLS + colg] = (u16)f2bf(v);
        else
          ((float*)Cout)[(size_t)row*NCOLS + colg] = v;
      }
      ps += v; pq += v*v;
    }
    if constexpr (STATS) {
      atomicAdd(&s_sum[colg], ps);
      atomicAdd(&s_sq[colg], pq);
    }
  }
  if constexpr (ATT) {
    float as_c[NF], ad_c[NF];
    #pragma unroll
    for (int nf = 0; nf < NF; nf++) { as_c[nf] = att_sv[nf*32+lm]; ad_c[nf] = att_dv[nf*32+lm]; }
    #pragma unroll
    for (int reg = 0; reg < 16; reg++) {
      float ps = 0.f, pd = 0.f;
      #pragma unroll
      for (int nf = 0; nf < NF; nf++) { float v = acc[nf][reg]; ps += v*as_c[nf]; pd += v*ad_c[nf]; }
      #pragma unroll
      for (int mm = 1; mm < 32; mm <<= 1) { ps += __shfl_xor(ps, mm); pd += __shfl_xor(pd, mm); }
      int row = row0 + wave*32 + (reg&3) + 8*(reg>>2) + 4*h;
      if (lm == 0 && row < M) { as_out[row] = ps; ad_out[row] = pd; }
    }
  }
  if constexpr (STATS) {
    __syncthreads();
    if (t < 128) { atomicAdd(gsum + t, s_sum[t]); atomicAdd(gsq + t, s_sq[t]); }
  }
}

// ======================= launch =======================
extern "C" void kernel_launch(void* const* d_in, const int* in_sizes, int n_in,
                              void* d_out, int out_size, void* d_ws, size_t ws_size,
                              hipStream_t stream) {
  const float* x       = (const float*)d_in[0];
  const int*   ei      = (const int*)d_in[1];
  const float* sage_Wl = (const float*)d_in[2];
  const float* sage_Wr = (const float*)d_in[3];
  const float* gcn_W   = (const float*)d_in[5];
  const float* gat_W   = (const float*)d_in[7];
  const float* att_s   = (const float*)d_in[8];
  const float* att_d   = (const float*)d_in[9];
  const float* bn1_g = (const float*)d_in[11], *bn1_b = (const float*)d_in[12];
  const float* bn2_g = (const float*)d_in[13], *bn2_b = (const float*)d_in[14];
  const float* bn3_g = (const float*)d_in[15], *bn3_b = (const float*)d_in[16];
  const float* lin1_W = (const float*)d_in[17], *lin1_b = (const float*)d_in[18];
  const float* lin2_W = (const float*)d_in[19], *lin2_b = (const float*)d_in[20];

  const int Nn = in_sizes[0] / Dd;     // 100000
  const int Ee = in_sizes[1] / 2;      // 600000
  const int* srcv = ei;
  const int* dstv = ei + Ee;

  u16* b0 = (u16*)d_ws;                        // N*128 bf16 each
  u16* b1 = b0 + (size_t)Nn*Dd;
  u16* b2 = b1 + (size_t)Nn*Dd;
  float* dinv  = (float*)(b2 + (size_t)Nn*Dd); // N
  float* a_s   = dinv + Nn;                    // N
  float* a_d   = a_s + Nn;                     // N
  float* bs    = a_d + Nn;                     // 6*128
  float* bs1_sum = bs,        *bs1_sq = bs + 128;
  float* bs2_sum = bs + 256,  *bs2_sq = bs + 384;
  float* bs3_sum = bs + 512,  *bs3_sq = bs + 640;
  int* rp    = (int*)(bs + 768);               // N+1
  int* cnt_i = rp + (Nn + 1);                  // N
  int* bsum  = cnt_i + Nn;                     // 64
  int* col   = bsum + 64;                      // E
  u16* wt_sWl = (u16*)(col + Ee);              // 128*128 each (frag order)
  u16* wt_sWr = wt_sWl + 128*128;
  u16* wt_gcn = wt_sWr + 128*128;
  u16* wt_gat = wt_gcn + 128*128;
  u16* wt_l1  = wt_gat + 128*128;              // 128*64

  const dim3 B(256);
  const dim3 Gn(CDIV(Nn, 256));
  const dim3 Gn32(CDIV(Nn*32, 256));
  const dim3 Ge(CDIV(Ee, 256));
  const dim3 Gmm(CDIV(Nn, 128));
  const dim3 Gstat(512);
  const int nscan = CDIV(Nn, 2048);

  // ---------- zeroing (once) ----------
  hipMemsetAsync(cnt_i, 0, (size_t)Nn*sizeof(int), stream);
  hipMemsetAsync(bs, 0, 768*sizeof(float), stream);

  // ---------- CSR + weight prep + x->bf16 ----------
  k_hist<<<Ge, B, 0, stream>>>(dstv, Ee, cnt_i);
  k_scan_l1<<<dim3(nscan), B, 0, stream>>>(cnt_i, rp, Nn, bsum);
  k_scan_l2<<<dim3(1), dim3(64), 0, stream>>>(bsum, nscan);
  k_scan_l3<<<dim3(nscan), B, 0, stream>>>(rp, Nn, bsum, Ee);
  k_fill<<<Ge, B, 0, stream>>>(srcv, dstv, Ee, rp, cnt_i, col);
  k_dinv<<<Gn, B, 0, stream>>>(rp, dinv, Nn);
  k_wt_all<<<dim3(288), B, 0, stream>>>(sage_Wl, sage_Wr, gcn_W, gat_W, lin1_W,
                                        wt_sWl, wt_sWr, wt_gcn, wt_gat, wt_l1);
  k_tobf16<<<dim3(CDIV(Nn*Dd/8, 256)), B, 0, stream>>>(x, b0, Nn*Dd/8);

  // ---------- Layer 1: SAGE ----------
  k_sage_gather<<<Gn32, B, 0, stream>>>(b0, rp, col, b1, Nn);   // mean -> b1
  k_mm<128, true, false, true, false, false, true, false><<<Gmm, B, 0, stream>>>(
      b1, b0, wt_sWl, wt_sWr, nullptr, nullptr, nullptr, nullptr, nullptr,
      b2, Nn, bs1_sum, bs1_sq, nullptr, nullptr, nullptr, nullptr, nullptr, nullptr);

  // ---------- Layer 2: GCN ----------
  k_mm<128, false, true, false, false, false, true, false><<<Gmm, B, 0, stream>>>(
      b2, nullptr, wt_gcn, nullptr, bn1_g, bn1_b, bs1_sum, bs1_sq, nullptr,
      b0, Nn, nullptr, nullptr, nullptr, nullptr, nullptr, nullptr, nullptr, nullptr);
  k_gcn_gather<<<Gn32, B, 0, stream>>>(b0, rp, col, dinv, b1, Nn);  // pre2 -> b1
  k_bn_stats_bf<<<Gstat, B, 0, stream>>>(b1, Nn, bs2_sum, bs2_sq);

  // ---------- Layer 3: GAT ----------
  k_mm<128, false, true, false, false, true, true, false><<<Gmm, B, 0, stream>>>(
      b1, nullptr, wt_gat, nullptr, bn2_g, bn2_b, bs2_sum, bs2_sq, nullptr,
      b2, Nn, nullptr, nullptr, att_s, att_d, a_s, a_d, nullptr, nullptr);
  k_gat_gather<<<Gn32, B, 0, stream>>>(b2, rp, col, a_s, a_d, b0, Nn);  // pre3 -> b0
  k_bn_stats_bf<<<Gstat, B, 0, stream>>>(b0, Nn, bs3_sum, bs3_sq);

  // ---------- MLP head (lin1 + lin2 + log_softmax fused) ----------
  k_mm<64, false, true, false, true, false, false, true><<<Gmm, B, 0, stream>>>(
      b0, nullptr, wt_l1, nullptr, bn3_g, bn3_b, bs3_sum, bs3_sq, lin1_b,
      (float*)d_out, Nn, nullptr, nullptr, nullptr, nullptr, nullptr, nullptr,
      lin2_W, lin2_b);
}

// Round 13
// 394.485 us; speedup vs baseline: 1.0129x; 1.0129x over previous
//
#include <hip/hip_runtime.h>

static constexpr int Dd = 128;   // feature dim
static constexpr int Hh = 64;    // MLP hidden
static constexpr int OC = 10;    // output classes
#define CDIV(a,b) (((a)+(b)-1)/(b))

typedef __attribute__((ext_vector_type(8))) short short8v;
typedef __attribute__((ext_vector_type(16))) float f32x16;
typedef unsigned short u16;

__device__ __forceinline__ float lrelu(float x){ return x>0.f? x : 0.2f*x; }
__device__ __forceinline__ unsigned f2bf(float f){
  unsigned u = __float_as_uint(f);
  return (u + 0x7FFFu + ((u>>16)&1u)) >> 16;
}
__device__ __forceinline__ float bl(unsigned u){ return __uint_as_float(u<<16); }
__device__ __forceinline__ float bh(unsigned u){ return __uint_as_float(u & 0xFFFF0000u); }

// ======================= CSR build =======================
__global__ __launch_bounds__(256) void k_hist(const int* __restrict__ dst, int E,
    int* __restrict__ cnt) {
  int e = blockIdx.x*256 + threadIdx.x;
  if (e < E) atomicAdd(cnt + dst[e], 1);
}

__global__ __launch_bounds__(256) void k_scan_l1(const int* __restrict__ cnt,
    int* __restrict__ rp, int n, int* __restrict__ bsum) {
  __shared__ int sdata[256];
  int t = threadIdx.x;
  int base = blockIdx.x*2048 + t*8;
  int v[8]; int s = 0;
  #pragma unroll
  for (int k = 0; k < 8; k++) { v[k] = (base+k < n) ? cnt[base+k] : 0; s += v[k]; }
  sdata[t] = s; __syncthreads();
  for (int off = 1; off < 256; off <<= 1) {
    int a = sdata[t];
    int b = (t >= off) ? sdata[t-off] : 0;
    __syncthreads();
    sdata[t] = a + b;
    __syncthreads();
  }
  int ex = sdata[t] - s;
  if (t == 255) bsum[blockIdx.x] = sdata[255];
  int run = ex;
  #pragma unroll
  for (int k = 0; k < 8; k++) { if (base+k < n) rp[base+k] = run; run += v[k]; }
}

__global__ void k_scan_l2(int* __restrict__ bsum, int nb) {
  if (threadIdx.x == 0 && blockIdx.x == 0) {
    int run = 0;
    for (int i = 0; i < nb; i++) { int v = bsum[i]; bsum[i] = run; run += v; }
  }
}

__global__ __launch_bounds__(256) void k_scan_l3(int* __restrict__ rp, int n,
    const int* __restrict__ bsum, int E) {
  int off = bsum[blockIdx.x];
  int base = blockIdx.x*2048 + threadIdx.x*8;
  #pragma unroll
  for (int k = 0; k < 8; k++) if (base+k < n) rp[base+k] += off;
  if (blockIdx.x == 0 && threadIdx.x == 0) rp[n] = E;
}

__global__ __launch_bounds__(256) void k_fill(const int* __restrict__ src,
    const int* __restrict__ dst, int E, const int* __restrict__ rp,
    int* __restrict__ cnt, int* __restrict__ col) {
  int e = blockIdx.x*256 + threadIdx.x;
  if (e >= E) return;
  int d = dst[e];
  int pos = rp[d] + atomicSub(cnt + d, 1) - 1;
  col[pos] = src[e];
}

__global__ __launch_bounds__(256) void k_dinv(const int* __restrict__ rp,
    float* __restrict__ dinv, int n) {
  int i = blockIdx.x*256 + threadIdx.x;
  if (i < n) dinv[i] = rsqrtf((float)(rp[i+1] - rp[i]) + 1.0f);
}

// ======================= weight prep: 32x32-MFMA fragment order =======================
// kc=k>>3 (16 chunks), nf=n>>5, lm=n&31: fi = ((kc*(N/32)+nf)*32+lm)*8 + (k&7)
__global__ __launch_bounds__(256) void k_wt_all(
    const float* __restrict__ w0, const float* __restrict__ w1,
    const float* __restrict__ w2, const float* __restrict__ w3,
    const float* __restrict__ w4,
    u16* __restrict__ o0, u16* __restrict__ o1, u16* __restrict__ o2,
    u16* __restrict__ o3, u16* __restrict__ o4) {
  int idx = blockIdx.x*256 + threadIdx.x;
  const float* W; u16* O; int base, N;
  if (idx < 65536) {
    int m = idx >> 14;
    W = m==0?w0 : m==1?w1 : m==2?w2 : w3;
    O = m==0?o0 : m==1?o1 : m==2?o2 : o3;
    base = idx & 16383; N = 128;
  } else if (idx < 73728) {
    W = w4; O = o4; base = idx - 65536; N = 64;
  } else return;
  int n = base / 128, k = base % 128;
  int kc = k >> 3, nf = n >> 5, lm = n & 31;
  int fi = (((kc*(N>>5) + nf)*32 + lm) << 3) | (k & 7);
  O[fi] = (u16)f2bf(W[k*N + n]);
}

// ======================= x -> bf16 =======================
__global__ __launch_bounds__(256) void k_tobf16(const float* __restrict__ in,
    u16* __restrict__ out, int n8) {
  int idx = blockIdx.x*256 + threadIdx.x;
  if (idx >= n8) return;
  const float4* p = reinterpret_cast<const float4*>(in) + idx*2;
  float4 v0 = p[0], v1 = p[1];
  uint4 w;
  w.x = f2bf(v0.x) | (f2bf(v0.y)<<16);
  w.y = f2bf(v0.z) | (f2bf(v0.w)<<16);
  w.z = f2bf(v1.x) | (f2bf(v1.y)<<16);
  w.w = f2bf(v1.z) | (f2bf(v1.w)<<16);
  reinterpret_cast<uint4*>(out)[idx] = w;
}

// ======================= gathers: 32 lanes/node, bf16 rows, unroll x4 =======================
__global__ __launch_bounds__(256) void k_sage_gather(const u16* __restrict__ xb,
    const int* __restrict__ rp, const int* __restrict__ col,
    u16* __restrict__ ob, int n) {
  int gid = blockIdx.x*256 + threadIdx.x;
  int i = gid >> 5, l = gid & 31;
  if (i >= n) return;
  int beg = rp[i], end = rp[i+1];
  const u16* xp = xb + l*4;
  float a0=0.f, a1=0.f, a2=0.f, a3=0.f;
  int j = beg;
  for (; j+4 <= end; j += 4) {
    int s0=col[j], s1=col[j+1], s2=col[j+2], s3=col[j+3];
    uint2 v0 = *reinterpret_cast<const uint2*>(xp + (size_t)s0*Dd);
    uint2 v1 = *reinterpret_cast<const uint2*>(xp + (size_t)s1*Dd);
    uint2 v2 = *reinterpret_cast<const uint2*>(xp + (size_t)s2*Dd);
    uint2 v3 = *reinterpret_cast<const uint2*>(xp + (size_t)s3*Dd);
    a0 += (bl(v0.x)+bl(v1.x)) + (bl(v2.x)+bl(v3.x));
    a1 += (bh(v0.x)+bh(v1.x)) + (bh(v2.x)+bh(v3.x));
    a2 += (bl(v0.y)+bl(v1.y)) + (bl(v2.y)+bl(v3.y));
    a3 += (bh(v0.y)+bh(v1.y)) + (bh(v2.y)+bh(v3.y));
  }
  for (; j < end; j++) {
    int s = col[j];
    uint2 v = *reinterpret_cast<const uint2*>(xp + (size_t)s*Dd);
    a0 += bl(v.x); a1 += bh(v.x); a2 += bl(v.y); a3 += bh(v.y);
  }
  float inv = 1.0f / fmaxf((float)(end - beg), 1.0f);
  uint2 o;
  o.x = f2bf(a0*inv) | (f2bf(a1*inv)<<16);
  o.y = f2bf(a2*inv) | (f2bf(a3*inv)<<16);
  *reinterpret_cast<uint2*>(ob + (size_t)i*Dd + l*4) = o;
}

__global__ __launch_bounds__(256) void k_gcn_gather(const u16* __restrict__ xb,
    const int* __restrict__ rp, const int* __restrict__ col,
    const float* __restrict__ dinv, u16* __restrict__ ob, int n) {
  int gid = blockIdx.x*256 + threadIdx.x;
  int i = gid >> 5, l = gid & 31;
  if (i >= n) return;
  int beg = rp[i], end = rp[i+1];
  const u16* xp = xb + l*4;
  float a0=0.f, a1=0.f, a2=0.f, a3=0.f;
  int j = beg;
  for (; j+4 <= end; j += 4) {
    int s0=col[j], s1=col[j+1], s2=col[j+2], s3=col[j+3];
    uint2 v0 = *reinterpret_cast<const uint2*>(xp + (size_t)s0*Dd);
    uint2 v1 = *reinterpret_cast<const uint2*>(xp + (size_t)s1*Dd);
    uint2 v2 = *reinterpret_cast<const uint2*>(xp + (size_t)s2*Dd);
    uint2 v3 = *reinterpret_cast<const uint2*>(xp + (size_t)s3*Dd);
    float w0 = dinv[s0], w1 = dinv[s1], w2 = dinv[s2], w3 = dinv[s3];
    a0 += (w0*bl(v0.x)+w1*bl(v1.x)) + (w2*bl(v2.x)+w3*bl(v3.x));
    a1 += (w0*bh(v0.x)+w1*bh(v1.x)) + (w2*bh(v2.x)+w3*bh(v3.x));
    a2 += (w0*bl(v0.y)+w1*bl(v1.y)) + (w2*bl(v2.y)+w3*bl(v3.y));
    a3 += (w0*bh(v0.y)+w1*bh(v1.y)) + (w2*bh(v2.y)+w3*bh(v3.y));
  }
  for (; j < end; j++) {
    int s = col[j];
    float w = dinv[s];
    uint2 v = *reinterpret_cast<const uint2*>(xp + (size_t)s*Dd);
    a0 += w*bl(v.x); a1 += w*bh(v.x); a2 += w*bl(v.y); a3 += w*bh(v.y);
  }
  float di = dinv[i];
  float ws = di*di;
  uint2 sv = *reinterpret_cast<const uint2*>(xp + (size_t)i*Dd);
  a0 = di*a0 + ws*bl(sv.x); a1 = di*a1 + ws*bh(sv.x);
  a2 = di*a2 + ws*bl(sv.y); a3 = di*a3 + ws*bh(sv.y);
  uint2 o;
  o.x = f2bf(a0) | (f2bf(a1)<<16);
  o.y = f2bf(a2) | (f2bf(a3)<<16);
  *reinterpret_cast<uint2*>(ob + (size_t)i*Dd + l*4) = o;
}

// single-pass online-softmax GAT gather
__global__ __launch_bounds__(256) void k_gat_gather(const u16* __restrict__ xb,
    const int* __restrict__ rp, const int* __restrict__ col,
    const float* __restrict__ a_s, const float* __restrict__ a_d,
    u16* __restrict__ ob, int n) {
  int gid = blockIdx.x*256 + threadIdx.x;
  int i = gid >> 5, l = gid & 31;
  if (i >= n) return;
  int beg = rp[i], end = rp[i+1];
  const u16* xp = xb + l*4;
  float ad = a_d[i];
  float m = lrelu(a_s[i] + ad);
  float z = 1.0f;
  uint2 sv = *reinterpret_cast<const uint2*>(xp + (size_t)i*Dd);
  float a0 = bl(sv.x), a1 = bh(sv.x), a2 = bl(sv.y), a3 = bh(sv.y);
  int j = beg;
  for (; j+4 <= end; j += 4) {
    int s0=col[j], s1=col[j+1], s2=col[j+2], s3=col[j+3];
    uint2 v0 = *reinterpret_cast<const uint2*>(xp + (size_t)s0*Dd);
    uint2 v1 = *reinterpret_cast<const uint2*>(xp + (size_t)s1*Dd);
    uint2 v2 = *reinterpret_cast<const uint2*>(xp + (size_t)s2*Dd);
    uint2 v3 = *reinterpret_cast<const uint2*>(xp + (size_t)s3*Dd);
    float e0 = lrelu(a_s[s0]+ad), e1 = lrelu(a_s[s1]+ad);
    float e2 = lrelu(a_s[s2]+ad), e3 = lrelu(a_s[s3]+ad);
    float mg = fmaxf(fmaxf(e0,e1), fmaxf(e2,e3));
    if (mg > m) {
      float r = __expf(m - mg);
      z *= r; a0 *= r; a1 *= r; a2 *= r; a3 *= r;
      m = mg;
    }
    float w0 = __expf(e0-m), w1 = __expf(e1-m);
    float w2 = __expf(e2-m), w3 = __expf(e3-m);
    z += (w0+w1) + (w2+w3);
    a0 += (w0*bl(v0.x)+w1*bl(v1.x)) + (w2*bl(v2.x)+w3*bl(v3.x));
    a1 += (w0*bh(v0.x)+w1*bh(v1.x)) + (w2*bh(v2.x)+w3*bh(v3.x));
    a2 += (w0*bl(v0.y)+w1*bl(v1.y)) + (w2*bl(v2.y)+w3*bl(v3.y));
    a3 += (w0*bh(v0.y)+w1*bh(v1.y)) + (w2*bh(v2.y)+w3*bh(v3.y));
  }
  for (; j < end; j++) {
    int s = col[j];
    uint2 v = *reinterpret_cast<const uint2*>(xp + (size_t)s*Dd);
    float e = lrelu(a_s[s]+ad);
    if (e > m) {
      float r = __expf(m - e);
      z *= r; a0 *= r; a1 *= r; a2 *= r; a3 *= r;
      m = e;
    }
    float w = __expf(e-m);
    z += w;
    a0 += w*bl(v.x); a1 += w*bh(v.x); a2 += w*bl(v.y); a3 += w*bh(v.y);
  }
  float inv = 1.0f / z;
  uint2 o;
  o.x = f2bf(a0*inv) | (f2bf(a1*inv)<<16);
  o.y = f2bf(a2*inv) | (f2bf(a3*inv)<<16);
  *reinterpret_cast<uint2*>(ob + (size_t)i*Dd + l*4) = o;
}

// ======================= BN stats over bf16 buffer =======================
__global__ __launch_bounds__(256) void k_bn_stats_bf(const u16* __restrict__ X, int M,
    float* __restrict__ gsum, float* __restrict__ gsq) {
  __shared__ float ss[2][256];
  int t = threadIdx.x;
  int cd = t & 63;
  int rg = t >> 6;
  float s0=0.f, q0=0.f, s1=0.f, q1=0.f;
  const unsigned* Xu = reinterpret_cast<const unsigned*>(X);
  for (int r = blockIdx.x*4 + rg; r < M; r += gridDim.x*4) {
    unsigned v = Xu[(size_t)r*64 + cd];
    float a = bl(v), b = bh(v);
    s0 += a; q0 += a*a; s1 += b; q1 += b*b;
  }
  ss[0][t] = s0; ss[1][t] = q0; __syncthreads();
  float rs0 = 0.f, rq0 = 0.f;
  if (rg == 0) {
    rs0 = ss[0][cd] + ss[0][cd+64] + ss[0][cd+128] + ss[0][cd+192];
    rq0 = ss[1][cd] + ss[1][cd+64] + ss[1][cd+128] + ss[1][cd+192];
  }
  __syncthreads();
  ss[0][t] = s1; ss[1][t] = q1; __syncthreads();
  if (rg == 0) {
    float rs1 = ss[0][cd] + ss[0][cd+64] + ss[0][cd+128] + ss[0][cd+192];
    float rq1 = ss[1][cd] + ss[1][cd+64] + ss[1][cd+128] + ss[1][cd+192];
    atomicAdd(gsum + 2*cd,     rs0); atomicAdd(gsq + 2*cd,     rq0);
    atomicAdd(gsum + 2*cd + 1, rs1); atomicAdd(gsq + 2*cd + 1, rq1);
  }
}

// ======================= MFMA GEMM v6: 64-row blocks, col-split waves =======================
// 64 rows/block, 4 waves: wave w -> rows (w&1)*32..+31, cols (w>>1)*NCOLS/2.
// A in padded LDS [64][136]u16 (272B stride, 0-conflict per r11 counter);
// W in LDS, staged linearly from fragment-order global (proven r8/r11).
// LDS ~= 50.8KB -> 3 blocks/CU (was 68.6 -> 2). s_aux unions BNA/STATS/ATT scratch.
template<int NCOLS, bool DUAL, bool BNA, bool STATS, bool BIASRELU, bool ATT, bool OUTBF, bool HEAD>
__global__ __launch_bounds__(256) void k_mm(
    const u16* __restrict__ A1, const u16* __restrict__ A2,
    const u16* __restrict__ WT1, const u16* __restrict__ WT2,
    const float* __restrict__ bng, const float* __restrict__ bnb,
    const float* __restrict__ bsum_in, const float* __restrict__ bsq_in,
    const float* __restrict__ bias,
    void* __restrict__ Cout, int M,
    float* __restrict__ gsum, float* __restrict__ gsq,
    const float* __restrict__ att_sv, const float* __restrict__ att_dv,
    float* __restrict__ as_out, float* __restrict__ ad_out,
    const float* __restrict__ W2, const float* __restrict__ b2) {
  constexpr int NF  = NCOLS/32;                // global col frags: 4 or 2
  constexpr int NFW = NF/2;                    // per-wave col frags: 2 or 1
  __shared__ char ldsA[64*272];                // 17.4KB padded A (m1 scratch in HEAD)
  __shared__ char ldsW[NCOLS*256];             // 32KB / 16KB
  __shared__ float s_aux[256];                 // BNA: scale|shift; STATS: sum|sq; ATT: as|ad
  int t = threadIdx.x;
  int wave = t >> 6, l = t & 63;
  int lm = l & 31, h = l >> 5;
  int rhalf = wave & 1, chalf = wave >> 1;
  int row0 = blockIdx.x*64;

  if constexpr (BNA) {
    if (t < 128) {
      float mu = bsum_in[t] / (float)M;
      float var = fmaxf(bsq_in[t] / (float)M - mu*mu, 0.f);
      float sc = bng[t] * rsqrtf(var + 1e-5f);
      s_aux[t] = sc;                   // scale
      s_aux[128 + t] = bnb[t] - mu*sc; // shift
    }
  }
  if constexpr (STATS) {
    s_aux[t] = 0.f;                    // sum[0..127], sq[128..255]
  }
  if (BNA || STATS) __syncthreads();

  f32x16 acc[NFW];
  #pragma unroll
  for (int nf = 0; nf < NFW; nf++)
    #pragma unroll
    for (int i = 0; i < 16; i++) acc[nf][i] = 0.f;

  const int nph = DUAL ? 2 : 1;
  for (int ph = 0; ph < nph; ph++) {
    if (ph) __syncthreads();
    const u16* A = (DUAL && ph) ? A2 : A1;
    const u16* WT = (DUAL && ph) ? WT2 : WT1;
    // ---- stage A: 1024 16B-chunks; global read coalesced; padded LDS ----
    #pragma unroll
    for (int i = 0; i < 4; i++) {
      int c = i*256 + t; int row = c >> 4; int k0 = (c & 15) << 3;
      uint4 w = {0,0,0,0};
      if (row0 + row < M)
        w = *reinterpret_cast<const uint4*>(A + (size_t)(row0+row)*128 + k0);
      if constexpr (BNA) {
        float4 sc0 = *reinterpret_cast<const float4*>(&s_aux[k0]);
        float4 sc1 = *reinterpret_cast<const float4*>(&s_aux[k0+4]);
        float4 sh0 = *reinterpret_cast<const float4*>(&s_aux[128+k0]);
        float4 sh1 = *reinterpret_cast<const float4*>(&s_aux[128+k0+4]);
        float e0 = fmaxf(bl(w.x)*sc0.x+sh0.x, 0.f), e1 = fmaxf(bh(w.x)*sc0.y+sh0.y, 0.f);
        float e2 = fmaxf(bl(w.y)*sc0.z+sh0.z, 0.f), e3 = fmaxf(bh(w.y)*sc0.w+sh0.w, 0.f);
        float e4 = fmaxf(bl(w.z)*sc1.x+sh1.x, 0.f), e5 = fmaxf(bh(w.z)*sc1.y+sh1.y, 0.f);
        float e6 = fmaxf(bl(w.w)*sc1.z+sh1.z, 0.f), e7 = fmaxf(bh(w.w)*sc1.w+sh1.w, 0.f);
        w.x = f2bf(e0) | (f2bf(e1)<<16);
        w.y = f2bf(e2) | (f2bf(e3)<<16);
        w.z = f2bf(e4) | (f2bf(e5)<<16);
        w.w = f2bf(e6) | (f2bf(e7)<<16);
      }
      *reinterpret_cast<uint4*>(ldsA + row*272 + k0*2) = w;
    }
    // ---- stage W: linear copy of fragment-order global ----
    #pragma unroll
    for (int i = 0; i < NCOLS/16; i++) {
      int c = i*256 + t;
      reinterpret_cast<uint4*>(ldsW)[c] = reinterpret_cast<const uint4*>(WT)[c];
    }
    __syncthreads();
    // ---- compute: 8 k-steps, NFW col-frags per wave ----
    #pragma unroll
    for (int ks = 0; ks < 8; ks++) {
      int kc = ks*2 + h;
      int arow = rhalf*32 + lm;
      short8v af = *reinterpret_cast<short8v*>(ldsA + arow*272 + kc*16);
      #pragma unroll
      for (int nfw = 0; nfw < NFW; nfw++) {
        int nf = chalf*NFW + nfw;
        short8v bf = *reinterpret_cast<short8v*>(ldsW + ((kc*NF + nf)*32 + lm)*16);
        acc[nfw] = __builtin_amdgcn_mfma_f32_32x32x16_bf16(af, bf, acc[nfw], 0, 0, 0);
      }
    }
  }
  // ---- epilogue ----
  if constexpr (HEAD) {
    __syncthreads();                           // A reads done; reuse ldsA for m1
    float* mrow = reinterpret_cast<float*>(ldsA);  // [64][65] = 16.6KB
    {
      int colg = chalf*32 + lm;                // NFW==1 here
      float bv = bias[colg];
      #pragma unroll
      for (int reg = 0; reg < 16; reg++) {
        int rowl = rhalf*32 + (reg&3) + 8*(reg>>2) + 4*h;
        mrow[rowl*65 + colg] = fmaxf(acc[0][reg] + bv, 0.f);
      }
    }
    __syncthreads();
    if (t < 64) {
      int row = row0 + t;
      if (row < M) {
        float p[OC];
        #pragma unroll
        for (int c = 0; c < OC; c++) p[c] = b2[c];   // uniform scalar loads
        for (int k = 0; k < Hh; k++) {
          float a = mrow[t*65 + k];
          #pragma unroll
          for (int c = 0; c < OC; c++) p[c] += a * W2[k*OC + c];
        }
        float mx = p[0];
        #pragma unroll
        for (int c = 1; c < OC; c++) mx = fmaxf(mx, p[c]);
        float s = 0.f;
        #pragma unroll
        for (int c = 0; c < OC; c++) s += __expf(p[c] - mx);
        float lse = mx + __logf(s);
        #pragma unroll
        for (int c = 0; c < OC; c++)
          ((float*)Cout)[(size_t)row*OC + c] = p[c] - lse;
      }
    }
    return;
  }
  #pragma unroll
  for (int nfw = 0; nfw < NFW; nfw++) {
    int colg = (chalf*NFW + nfw)*32 + lm;
    float bv = 0.f;
    if constexpr (BIASRELU) bv = bias[colg];
    float ps = 0.f, pq = 0.f;
    #pragma unroll
    for (int reg = 0; reg < 16; reg++) {
      int row = row0 + rhalf*32 + (reg&3) + 8*(reg>>2) + 4*h;
      float v = acc[nfw][reg];
      if constexpr (BIASRELU) v = fmaxf(v + bv, 0.f);
      if (row < M) {
        if constexpr (OUTBF)
          ((u16*)Cout)[(size_t)row*NCOLS + colg] = (u16)f2bf(v);
        else
          ((float*)Cout)[(size_t)row*NCOLS + colg] = v;
      }
      ps += v; pq += v*v;
    }
    if constexpr (STATS) {
      atomicAdd(&s_aux[colg], ps);
      atomicAdd(&s_aux[128 + colg], pq);
    }
  }
  if constexpr (ATT) {
    __syncthreads();                 // scale/shift no longer needed
    if (t < 128) s_aux[t] = 0.f;     // as[0..63], ad[64..127]
    __syncthreads();
    float as_c[NFW], ad_c[NFW];
    #pragma unroll
    for (int nfw = 0; nfw < NFW; nfw++) {
      int colg = (chalf*NFW + nfw)*32 + lm;
      as_c[nfw] = att_sv[colg]; ad_c[nfw] = att_dv[colg];
    }
    #pragma unroll
    for (int reg = 0; reg < 16; reg++) {
      float ps = 0.f, pd = 0.f;
      #pragma unroll
      for (int nfw = 0; nfw < NFW; nfw++) {
        float v = acc[nfw][reg]; ps += v*as_c[nfw]; pd += v*ad_c[nfw];
      }
      #pragma unroll
      for (int mm = 1; mm < 32; mm <<= 1) { ps += __shfl_xor(ps, mm); pd += __shfl_xor(pd, mm); }
      int rowl = rhalf*32 + (reg&3) + 8*(reg>>2) + 4*h;
      if (lm == 0) { atomicAdd(&s_aux[rowl], ps); atomicAdd(&s_aux[64 + rowl], pd); }
    }
    __syncthreads();
    if (t < 64 && row0 + t < M) {
      as_out[row0 + t] = s_aux[t];
      ad_out[row0 + t] = s_aux[64 + t];
    }
  }
  if constexpr (STATS) {
    __syncthreads();
    if (t < 128) { atomicAdd(gsum + t, s_aux[t]); atomicAdd(gsq + t, s_aux[128 + t]); }
  }
}

// ======================= launch =======================
extern "C" void kernel_launch(void* const* d_in, const int* in_sizes, int n_in,
                              void* d_out, int out_size, void* d_ws, size_t ws_size,
                              hipStream_t stream) {
  const float* x       = (const float*)d_in[0];
  const int*   ei      = (const int*)d_in[1];
  const float* sage_Wl = (const float*)d_in[2];
  const float* sage_Wr = (const float*)d_in[3];
  const float* gcn_W   = (const float*)d_in[5];
  const float* gat_W   = (const float*)d_in[7];
  const float* att_s   = (const float*)d_in[8];
  const float* att_d   = (const float*)d_in[9];
  const float* bn1_g = (const float*)d_in[11], *bn1_b = (const float*)d_in[12];
  const float* bn2_g = (const float*)d_in[13], *bn2_b = (const float*)d_in[14];
  const float* bn3_g = (const float*)d_in[15], *bn3_b = (const float*)d_in[16];
  const float* lin1_W = (const float*)d_in[17], *lin1_b = (const float*)d_in[18];
  const float* lin2_W = (const float*)d_in[19], *lin2_b = (const float*)d_in[20];

  const int Nn = in_sizes[0] / Dd;     // 100000
  const int Ee = in_sizes[1] / 2;      // 600000
  const int* srcv = ei;
  const int* dstv = ei + Ee;

  u16* b0 = (u16*)d_ws;                        // N*128 bf16 each
  u16* b1 = b0 + (size_t)Nn*Dd;
  u16* b2 = b1 + (size_t)Nn*Dd;
  float* dinv  = (float*)(b2 + (size_t)Nn*Dd); // N
  float* a_s   = dinv + Nn;                    // N
  float* a_d   = a_s + Nn;                     // N
  float* bs    = a_d + Nn;                     // 6*128
  float* bs1_sum = bs,        *bs1_sq = bs + 128;
  float* bs2_sum = bs + 256,  *bs2_sq = bs + 384;
  float* bs3_sum = bs + 512,  *bs3_sq = bs + 640;
  int* rp    = (int*)(bs + 768);               // N+1
  int* cnt_i = rp + (Nn + 1);                  // N
  int* bsum  = cnt_i + Nn;                     // 64
  int* col   = bsum + 64;                      // E
  u16* wt_sWl = (u16*)(col + Ee);              // 128*128 each (frag order)
  u16* wt_sWr = wt_sWl + 128*128;
  u16* wt_gcn = wt_sWr + 128*128;
  u16* wt_gat = wt_gcn + 128*128;
  u16* wt_l1  = wt_gat + 128*128;              // 128*64

  const dim3 B(256);
  const dim3 Gn(CDIV(Nn, 256));
  const dim3 Gn32(CDIV(Nn*32, 256));
  const dim3 Ge(CDIV(Ee, 256));
  const dim3 Gmm(CDIV(Nn, 64));
  const dim3 Gstat(512);
  const int nscan = CDIV(Nn, 2048);

  // ---------- zeroing (once) ----------
  hipMemsetAsync(cnt_i, 0, (size_t)Nn*sizeof(int), stream);
  hipMemsetAsync(bs, 0, 768*sizeof(float), stream);

  // ---------- CSR + weight prep + x->bf16 ----------
  k_hist<<<Ge, B, 0, stream>>>(dstv, Ee, cnt_i);
  k_scan_l1<<<dim3(nscan), B, 0, stream>>>(cnt_i, rp, Nn, bsum);
  k_scan_l2<<<dim3(1), dim3(64), 0, stream>>>(bsum, nscan);
  k_scan_l3<<<dim3(nscan), B, 0, stream>>>(rp, Nn, bsum, Ee);
  k_fill<<<Ge, B, 0, stream>>>(srcv, dstv, Ee, rp, cnt_i, col);
  k_dinv<<<Gn, B, 0, stream>>>(rp, dinv, Nn);
  k_wt_all<<<dim3(288), B, 0, stream>>>(sage_Wl, sage_Wr, gcn_W, gat_W, lin1_W,
                                        wt_sWl, wt_sWr, wt_gcn, wt_gat, wt_l1);
  k_tobf16<<<dim3(CDIV(Nn*Dd/8, 256)), B, 0, stream>>>(x, b0, Nn*Dd/8);

  // ---------- Layer 1: SAGE ----------
  k_sage_gather<<<Gn32, B, 0, stream>>>(b0, rp, col, b1, Nn);   // mean -> b1
  k_mm<128, true, false, true, false, false, true, false><<<Gmm, B, 0, stream>>>(
      b1, b0, wt_sWl, wt_sWr, nullptr, nullptr, nullptr, nullptr, nullptr,
      b2, Nn, bs1_sum, bs1_sq, nullptr, nullptr, nullptr, nullptr, nullptr, nullptr);

  // ---------- Layer 2: GCN ----------
  k_mm<128, false, true, false, false, false, true, false><<<Gmm, B, 0, stream>>>(
      b2, nullptr, wt_gcn, nullptr, bn1_g, bn1_b, bs1_sum, bs1_sq, nullptr,
      b0, Nn, nullptr, nullptr, nullptr, nullptr, nullptr, nullptr, nullptr, nullptr);
  k_gcn_gather<<<Gn32, B, 0, stream>>>(b0, rp, col, dinv, b1, Nn);  // pre2 -> b1
  k_bn_stats_bf<<<Gstat, B, 0, stream>>>(b1, Nn, bs2_sum, bs2_sq);

  // ---------- Layer 3: GAT ----------
  k_mm<128, false, true, false, false, true, true, false><<<Gmm, B, 0, stream>>>(
      b1, nullptr, wt_gat, nullptr, bn2_g, bn2_b, bs2_sum, bs2_sq, nullptr,
      b2, Nn, nullptr, nullptr, att_s, att_d, a_s, a_d, nullptr, nullptr);
  k_gat_gather<<<Gn32, B, 0, stream>>>(b2, rp, col, a_s, a_d, b0, Nn);  // pre3 -> b0
  k_bn_stats_bf<<<Gstat, B, 0, stream>>>(b0, Nn, bs3_sum, bs3_sq);

  // ---------- MLP head (lin1 + lin2 + log_softmax fused) ----------
  k_mm<64, false, true, false, true, false, false, true><<<Gmm, B, 0, stream>>>(
      b0, nullptr, wt_l1, nullptr, bn3_g, bn3_b, bs3_sum, bs3_sq, lin1_b,
      (float*)d_out, Nn, nullptr, nullptr, nullptr, nullptr, nullptr, nullptr,
      lin2_W, lin2_b);
}

// Round 14
// 379.756 us; speedup vs baseline: 1.0522x; 1.0388x over previous
//
#include <hip/hip_runtime.h>

static constexpr int Dd = 128;   // feature dim
static constexpr int Hh = 64;    // MLP hidden
static constexpr int OC = 10;    // output classes
#define CDIV(a,b) (((a)+(b)-1)/(b))

typedef __attribute__((ext_vector_type(8))) short short8v;
typedef __attribute__((ext_vector_type(16))) float f32x16;
typedef unsigned short u16;

__device__ __forceinline__ float lrelu(float x){ return x>0.f? x : 0.2f*x; }
__device__ __forceinline__ unsigned f2bf(float f){
  unsigned u = __float_as_uint(f);
  return (u + 0x7FFFu + ((u>>16)&1u)) >> 16;
}
__device__ __forceinline__ float bl(unsigned u){ return __uint_as_float(u<<16); }
__device__ __forceinline__ float bh(unsigned u){ return __uint_as_float(u & 0xFFFF0000u); }

// ======================= CSR build =======================
__global__ __launch_bounds__(256) void k_hist(const int* __restrict__ dst, int E,
    int* __restrict__ cnt) {
  int e = blockIdx.x*256 + threadIdx.x;
  if (e < E) atomicAdd(cnt + dst[e], 1);
}

__global__ __launch_bounds__(256) void k_scan_l1(const int* __restrict__ cnt,
    int* __restrict__ rp, int n, int* __restrict__ bsum) {
  __shared__ int sdata[256];
  int t = threadIdx.x;
  int base = blockIdx.x*2048 + t*8;
  int v[8]; int s = 0;
  #pragma unroll
  for (int k = 0; k < 8; k++) { v[k] = (base+k < n) ? cnt[base+k] : 0; s += v[k]; }
  sdata[t] = s; __syncthreads();
  for (int off = 1; off < 256; off <<= 1) {
    int a = sdata[t];
    int b = (t >= off) ? sdata[t-off] : 0;
    __syncthreads();
    sdata[t] = a + b;
    __syncthreads();
  }
  int ex = sdata[t] - s;
  if (t == 255) bsum[blockIdx.x] = sdata[255];
  int run = ex;
  #pragma unroll
  for (int k = 0; k < 8; k++) { if (base+k < n) rp[base+k] = run; run += v[k]; }
}

__global__ void k_scan_l2(int* __restrict__ bsum, int nb) {
  if (threadIdx.x == 0 && blockIdx.x == 0) {
    int run = 0;
    for (int i = 0; i < nb; i++) { int v = bsum[i]; bsum[i] = run; run += v; }
  }
}

__global__ __launch_bounds__(256) void k_scan_l3(int* __restrict__ rp, int n,
    const int* __restrict__ bsum, int E) {
  int off = bsum[blockIdx.x];
  int base = blockIdx.x*2048 + threadIdx.x*8;
  #pragma unroll
  for (int k = 0; k < 8; k++) if (base+k < n) rp[base+k] += off;
  if (blockIdx.x == 0 && threadIdx.x == 0) rp[n] = E;
}

__global__ __launch_bounds__(256) void k_fill(const int* __restrict__ src,
    const int* __restrict__ dst, int E, const int* __restrict__ rp,
    int* __restrict__ cnt, int* __restrict__ col) {
  int e = blockIdx.x*256 + threadIdx.x;
  if (e >= E) return;
  int d = dst[e];
  int pos = rp[d] + atomicSub(cnt + d, 1) - 1;
  col[pos] = src[e];
}

__global__ __launch_bounds__(256) void k_dinv(const int* __restrict__ rp,
    float* __restrict__ dinv, int n) {
  int i = blockIdx.x*256 + threadIdx.x;
  if (i < n) dinv[i] = rsqrtf((float)(rp[i+1] - rp[i]) + 1.0f);
}

// ======================= weight prep: 32x32-MFMA fragment order =======================
__global__ __launch_bounds__(256) void k_wt_all(
    const float* __restrict__ w0, const float* __restrict__ w1,
    const float* __restrict__ w2, const float* __restrict__ w3,
    const float* __restrict__ w4,
    u16* __restrict__ o0, u16* __restrict__ o1, u16* __restrict__ o2,
    u16* __restrict__ o3, u16* __restrict__ o4) {
  int idx = blockIdx.x*256 + threadIdx.x;
  const float* W; u16* O; int base, N;
  if (idx < 65536) {
    int m = idx >> 14;
    W = m==0?w0 : m==1?w1 : m==2?w2 : w3;
    O = m==0?o0 : m==1?o1 : m==2?o2 : o3;
    base = idx & 16383; N = 128;
  } else if (idx < 73728) {
    W = w4; O = o4; base = idx - 65536; N = 64;
  } else return;
  int n = base / 128, k = base % 128;
  int kc = k >> 3, nf = n >> 5, lm = n & 31;
  int fi = (((kc*(N>>5) + nf)*32 + lm) << 3) | (k & 7);
  O[fi] = (u16)f2bf(W[k*N + n]);
}

// ======================= x -> bf16 =======================
__global__ __launch_bounds__(256) void k_tobf16(const float* __restrict__ in,
    u16* __restrict__ out, int n8) {
  int idx = blockIdx.x*256 + threadIdx.x;
  if (idx >= n8) return;
  const float4* p = reinterpret_cast<const float4*>(in) + idx*2;
  float4 v0 = p[0], v1 = p[1];
  uint4 w;
  w.x = f2bf(v0.x) | (f2bf(v0.y)<<16);
  w.y = f2bf(v0.z) | (f2bf(v0.w)<<16);
  w.z = f2bf(v1.x) | (f2bf(v1.y)<<16);
  w.w = f2bf(v1.z) | (f2bf(v1.w)<<16);
  reinterpret_cast<uint4*>(out)[idx] = w;
}

// ======================= gathers: 32 lanes/node, software-pipelined x4 =======================
__global__ __launch_bounds__(256) void k_sage_gather(const u16* __restrict__ xb,
    const int* __restrict__ rp, const int* __restrict__ col,
    u16* __restrict__ ob, int n) {
  int gid = blockIdx.x*256 + threadIdx.x;
  int i = gid >> 5, l = gid & 31;
  if (i >= n) return;
  int beg = rp[i], end = rp[i+1];
  const u16* xp = xb + l*4;
  float a0=0.f, a1=0.f, a2=0.f, a3=0.f;
  int j = beg;
  if (j + 4 <= end) {
    int s0=col[j], s1=col[j+1], s2=col[j+2], s3=col[j+3];
    uint2 c0 = *reinterpret_cast<const uint2*>(xp + (size_t)s0*Dd);
    uint2 c1 = *reinterpret_cast<const uint2*>(xp + (size_t)s1*Dd);
    uint2 c2 = *reinterpret_cast<const uint2*>(xp + (size_t)s2*Dd);
    uint2 c3 = *reinterpret_cast<const uint2*>(xp + (size_t)s3*Dd);
    j += 4;
    for (; j + 4 <= end; j += 4) {
      int t0=col[j], t1=col[j+1], t2=col[j+2], t3=col[j+3];
      uint2 n0 = *reinterpret_cast<const uint2*>(xp + (size_t)t0*Dd);
      uint2 n1 = *reinterpret_cast<const uint2*>(xp + (size_t)t1*Dd);
      uint2 n2 = *reinterpret_cast<const uint2*>(xp + (size_t)t2*Dd);
      uint2 n3 = *reinterpret_cast<const uint2*>(xp + (size_t)t3*Dd);
      a0 += (bl(c0.x)+bl(c1.x)) + (bl(c2.x)+bl(c3.x));
      a1 += (bh(c0.x)+bh(c1.x)) + (bh(c2.x)+bh(c3.x));
      a2 += (bl(c0.y)+bl(c1.y)) + (bl(c2.y)+bl(c3.y));
      a3 += (bh(c0.y)+bh(c1.y)) + (bh(c2.y)+bh(c3.y));
      c0=n0; c1=n1; c2=n2; c3=n3;
    }
    a0 += (bl(c0.x)+bl(c1.x)) + (bl(c2.x)+bl(c3.x));
    a1 += (bh(c0.x)+bh(c1.x)) + (bh(c2.x)+bh(c3.x));
    a2 += (bl(c0.y)+bl(c1.y)) + (bl(c2.y)+bl(c3.y));
    a3 += (bh(c0.y)+bh(c1.y)) + (bh(c2.y)+bh(c3.y));
  }
  for (; j < end; j++) {
    int s = col[j];
    uint2 v = *reinterpret_cast<const uint2*>(xp + (size_t)s*Dd);
    a0 += bl(v.x); a1 += bh(v.x); a2 += bl(v.y); a3 += bh(v.y);
  }
  float inv = 1.0f / fmaxf((float)(end - beg), 1.0f);
  uint2 o;
  o.x = f2bf(a0*inv) | (f2bf(a1*inv)<<16);
  o.y = f2bf(a2*inv) | (f2bf(a3*inv)<<16);
  *reinterpret_cast<uint2*>(ob + (size_t)i*Dd + l*4) = o;
}

__global__ __launch_bounds__(256) void k_gcn_gather(const u16* __restrict__ xb,
    const int* __restrict__ rp, const int* __restrict__ col,
    const float* __restrict__ dinv, u16* __restrict__ ob, int n) {
  int gid = blockIdx.x*256 + threadIdx.x;
  int i = gid >> 5, l = gid & 31;
  if (i >= n) return;
  int beg = rp[i], end = rp[i+1];
  const u16* xp = xb + l*4;
  float a0=0.f, a1=0.f, a2=0.f, a3=0.f;
  int j = beg;
  if (j + 4 <= end) {
    int s0=col[j], s1=col[j+1], s2=col[j+2], s3=col[j+3];
    uint2 c0 = *reinterpret_cast<const uint2*>(xp + (size_t)s0*Dd);
    uint2 c1 = *reinterpret_cast<const uint2*>(xp + (size_t)s1*Dd);
    uint2 c2 = *reinterpret_cast<const uint2*>(xp + (size_t)s2*Dd);
    uint2 c3 = *reinterpret_cast<const uint2*>(xp + (size_t)s3*Dd);
    float w0 = dinv[s0], w1 = dinv[s1], w2 = dinv[s2], w3 = dinv[s3];
    j += 4;
    for (; j + 4 <= end; j += 4) {
      int t0=col[j], t1=col[j+1], t2=col[j+2], t3=col[j+3];
      uint2 n0 = *reinterpret_cast<const uint2*>(xp + (size_t)t0*Dd);
      uint2 n1 = *reinterpret_cast<const uint2*>(xp + (size_t)t1*Dd);
      uint2 n2 = *reinterpret_cast<const uint2*>(xp + (size_t)t2*Dd);
      uint2 n3 = *reinterpret_cast<const uint2*>(xp + (size_t)t3*Dd);
      float x0 = dinv[t0], x1 = dinv[t1], x2 = dinv[t2], x3 = dinv[t3];
      a0 += (w0*bl(c0.x)+w1*bl(c1.x)) + (w2*bl(c2.x)+w3*bl(c3.x));
      a1 += (w0*bh(c0.x)+w1*bh(c1.x)) + (w2*bh(c2.x)+w3*bh(c3.x));
      a2 += (w0*bl(c0.y)+w1*bl(c1.y)) + (w2*bl(c2.y)+w3*bl(c3.y));
      a3 += (w0*bh(c0.y)+w1*bh(c1.y)) + (w2*bh(c2.y)+w3*bh(c3.y));
      c0=n0; c1=n1; c2=n2; c3=n3;
      w0=x0; w1=x1; w2=x2; w3=x3;
    }
    a0 += (w0*bl(c0.x)+w1*bl(c1.x)) + (w2*bl(c2.x)+w3*bl(c3.x));
    a1 += (w0*bh(c0.x)+w1*bh(c1.x)) + (w2*bh(c2.x)+w3*bh(c3.x));
    a2 += (w0*bl(c0.y)+w1*bl(c1.y)) + (w2*bl(c2.y)+w3*bl(c3.y));
    a3 += (w0*bh(c0.y)+w1*bh(c1.y)) + (w2*bh(c2.y)+w3*bh(c3.y));
  }
  for (; j < end; j++) {
    int s = col[j];
    float w = dinv[s];
    uint2 v = *reinterpret_cast<const uint2*>(xp + (size_t)s*Dd);
    a0 += w*bl(v.x); a1 += w*bh(v.x); a2 += w*bl(v.y); a3 += w*bh(v.y);
  }
  float di = dinv[i];
  float ws = di*di;
  uint2 sv = *reinterpret_cast<const uint2*>(xp + (size_t)i*Dd);
  a0 = di*a0 + ws*bl(sv.x); a1 = di*a1 + ws*bh(sv.x);
  a2 = di*a2 + ws*bl(sv.y); a3 = di*a3 + ws*bh(sv.y);
  uint2 o;
  o.x = f2bf(a0) | (f2bf(a1)<<16);
  o.y = f2bf(a2) | (f2bf(a3)<<16);
  *reinterpret_cast<uint2*>(ob + (size_t)i*Dd + l*4) = o;
}

// single-pass online-softmax GAT gather, software-pipelined
__global__ __launch_bounds__(256) void k_gat_gather(const u16* __restrict__ xb,
    const int* __restrict__ rp, const int* __restrict__ col,
    const float* __restrict__ a_s, const float* __restrict__ a_d,
    u16* __restrict__ ob, int n) {
  int gid = blockIdx.x*256 + threadIdx.x;
  int i = gid >> 5, l = gid & 31;
  if (i >= n) return;
  int beg = rp[i], end = rp[i+1];
  const u16* xp = xb + l*4;
  float ad = a_d[i];
  float m = lrelu(a_s[i] + ad);
  float z = 1.0f;
  uint2 sv = *reinterpret_cast<const uint2*>(xp + (size_t)i*Dd);
  float a0 = bl(sv.x), a1 = bh(sv.x), a2 = bl(sv.y), a3 = bh(sv.y);
  int j = beg;
  if (j + 4 <= end) {
    int s0=col[j], s1=col[j+1], s2=col[j+2], s3=col[j+3];
    uint2 c0 = *reinterpret_cast<const uint2*>(xp + (size_t)s0*Dd);
    uint2 c1 = *reinterpret_cast<const uint2*>(xp + (size_t)s1*Dd);
    uint2 c2 = *reinterpret_cast<const uint2*>(xp + (size_t)s2*Dd);
    uint2 c3 = *reinterpret_cast<const uint2*>(xp + (size_t)s3*Dd);
    float f0 = a_s[s0], f1 = a_s[s1], f2 = a_s[s2], f3 = a_s[s3];
    j += 4;
    for (; j + 4 <= end; j += 4) {
      int t0=col[j], t1=col[j+1], t2=col[j+2], t3=col[j+3];
      uint2 n0 = *reinterpret_cast<const uint2*>(xp + (size_t)t0*Dd);
      uint2 n1 = *reinterpret_cast<const uint2*>(xp + (size_t)t1*Dd);
      uint2 n2 = *reinterpret_cast<const uint2*>(xp + (size_t)t2*Dd);
      uint2 n3 = *reinterpret_cast<const uint2*>(xp + (size_t)t3*Dd);
      float g0 = a_s[t0], g1 = a_s[t1], g2 = a_s[t2], g3 = a_s[t3];
      float e0 = lrelu(f0+ad), e1 = lrelu(f1+ad);
      float e2 = lrelu(f2+ad), e3 = lrelu(f3+ad);
      float mg = fmaxf(fmaxf(e0,e1), fmaxf(e2,e3));
      if (mg > m) {
        float r = __expf(m - mg);
        z *= r; a0 *= r; a1 *= r; a2 *= r; a3 *= r;
        m = mg;
      }
      float w0 = __expf(e0-m), w1 = __expf(e1-m);
      float w2 = __expf(e2-m), w3 = __expf(e3-m);
      z += (w0+w1) + (w2+w3);
      a0 += (w0*bl(c0.x)+w1*bl(c1.x)) + (w2*bl(c2.x)+w3*bl(c3.x));
      a1 += (w0*bh(c0.x)+w1*bh(c1.x)) + (w2*bh(c2.x)+w3*bh(c3.x));
      a2 += (w0*bl(c0.y)+w1*bl(c1.y)) + (w2*bl(c2.y)+w3*bl(c3.y));
      a3 += (w0*bh(c0.y)+w1*bh(c1.y)) + (w2*bh(c2.y)+w3*bh(c3.y));
      c0=n0; c1=n1; c2=n2; c3=n3;
      f0=g0; f1=g1; f2=g2; f3=g3;
    }
    float e0 = lrelu(f0+ad), e1 = lrelu(f1+ad);
    float e2 = lrelu(f2+ad), e3 = lrelu(f3+ad);
    float mg = fmaxf(fmaxf(e0,e1), fmaxf(e2,e3));
    if (mg > m) {
      float r = __expf(m - mg);
      z *= r; a0 *= r; a1 *= r; a2 *= r; a3 *= r;
      m = mg;
    }
    float w0 = __expf(e0-m), w1 = __expf(e1-m);
    float w2 = __expf(e2-m), w3 = __expf(e3-m);
    z += (w0+w1) + (w2+w3);
    a0 += (w0*bl(c0.x)+w1*bl(c1.x)) + (w2*bl(c2.x)+w3*bl(c3.x));
    a1 += (w0*bh(c0.x)+w1*bh(c1.x)) + (w2*bh(c2.x)+w3*bh(c3.x));
    a2 += (w0*bl(c0.y)+w1*bl(c1.y)) + (w2*bl(c2.y)+w3*bl(c3.y));
    a3 += (w0*bh(c0.y)+w1*bh(c1.y)) + (w2*bh(c2.y)+w3*bh(c3.y));
  }
  for (; j < end; j++) {
    int s = col[j];
    uint2 v = *reinterpret_cast<const uint2*>(xp + (size_t)s*Dd);
    float e = lrelu(a_s[s]+ad);
    if (e > m) {
      float r = __expf(m - e);
      z *= r; a0 *= r; a1 *= r; a2 *= r; a3 *= r;
      m = e;
    }
    float w = __expf(e-m);
    z += w;
    a0 += w*bl(v.x); a1 += w*bh(v.x); a2 += w*bl(v.y); a3 += w*bh(v.y);
  }
  float inv = 1.0f / z;
  uint2 o;
  o.x = f2bf(a0*inv) | (f2bf(a1*inv)<<16);
  o.y = f2bf(a2*inv) | (f2bf(a3*inv)<<16);
  *reinterpret_cast<uint2*>(ob + (size_t)i*Dd + l*4) = o;
}

// ======================= BN stats over bf16 buffer =======================
__global__ __launch_bounds__(256) void k_bn_stats_bf(const u16* __restrict__ X, int M,
    float* __restrict__ gsum, float* __restrict__ gsq) {
  __shared__ float ss[2][256];
  int t = threadIdx.x;
  int cd = t & 63;
  int rg = t >> 6;
  float s0=0.f, q0=0.f, s1=0.f, q1=0.f;
  const unsigned* Xu = reinterpret_cast<const unsigned*>(X);
  for (int r = blockIdx.x*4 + rg; r < M; r += gridDim.x*4) {
    unsigned v = Xu[(size_t)r*64 + cd];
    float a = bl(v), b = bh(v);
    s0 += a; q0 += a*a; s1 += b; q1 += b*b;
  }
  ss[0][t] = s0; ss[1][t] = q0; __syncthreads();
  float rs0 = 0.f, rq0 = 0.f;
  if (rg == 0) {
    rs0 = ss[0][cd] + ss[0][cd+64] + ss[0][cd+128] + ss[0][cd+192];
    rq0 = ss[1][cd] + ss[1][cd+64] + ss[1][cd+128] + ss[1][cd+192];
  }
  __syncthreads();
  ss[0][t] = s1; ss[1][t] = q1; __syncthreads();
  if (rg == 0) {
    float rs1 = ss[0][cd] + ss[0][cd+64] + ss[0][cd+128] + ss[0][cd+192];
    float rq1 = ss[1][cd] + ss[1][cd+64] + ss[1][cd+128] + ss[1][cd+192];
    atomicAdd(gsum + 2*cd,     rs0); atomicAdd(gsq + 2*cd,     rq0);
    atomicAdd(gsum + 2*cd + 1, rs1); atomicAdd(gsq + 2*cd + 1, rq1);
  }
}

// ======================= MFMA GEMM (r11-proven): A padded LDS + W LDS =======================
// 128 rows/block, 4 waves, 32x32x16. A staged to padded LDS [128][136]u16
// (row stride 272B -> conflict-free fragment reads). W staged linearly from
// fragment-order global (conflict-free both ways). HEAD: fused lin2+log_softmax.
template<int NCOLS, bool DUAL, bool BNA, bool STATS, bool BIASRELU, bool ATT, bool OUTBF, bool HEAD>
__global__ __launch_bounds__(256) void k_mm(
    const u16* __restrict__ A1, const u16* __restrict__ A2,
    const u16* __restrict__ WT1, const u16* __restrict__ WT2,
    const float* __restrict__ bng, const float* __restrict__ bnb,
    const float* __restrict__ bsum_in, const float* __restrict__ bsq_in,
    const float* __restrict__ bias,
    void* __restrict__ Cout, int M,
    float* __restrict__ gsum, float* __restrict__ gsq,
    const float* __restrict__ att_sv, const float* __restrict__ att_dv,
    float* __restrict__ as_out, float* __restrict__ ad_out,
    const float* __restrict__ W2, const float* __restrict__ b2) {
  constexpr int NF = NCOLS/32;                 // 4 or 2
  __shared__ char ldsA[128*272];               // 34.8KB padded A (m1 scratch in HEAD)
  __shared__ char ldsW[NCOLS*256];             // 32KB / 16KB
  __shared__ float s_scale[128], s_shift[128];
  __shared__ float s_sum[128], s_sq[128];
  __shared__ float w2s[Hh][OC];
  __shared__ float b2s[OC];
  int t = threadIdx.x;
  int wave = t >> 6, l = t & 63;
  int lm = l & 31, h = l >> 5;
  int row0 = blockIdx.x*128;

  if constexpr (BNA) {
    if (t < 128) {
      float mu = bsum_in[t] / (float)M;
      float var = fmaxf(bsq_in[t] / (float)M - mu*mu, 0.f);
      float sc = bng[t] * rsqrtf(var + 1e-5f);
      s_scale[t] = sc;
      s_shift[t] = bnb[t] - mu*sc;
    }
  }
  if constexpr (STATS) {
    if (t < 128) { s_sum[t] = 0.f; s_sq[t] = 0.f; }
  }
  if constexpr (HEAD) {
    for (int i = t; i < Hh*OC; i += 256) w2s[i/OC][i%OC] = W2[i];
    if (t < OC) b2s[t] = b2[t];
  }
  if (BNA || STATS || HEAD) __syncthreads();

  f32x16 acc[NF];
  #pragma unroll
  for (int nf = 0; nf < NF; nf++)
    #pragma unroll
    for (int i = 0; i < 16; i++) acc[nf][i] = 0.f;

  const int nph = DUAL ? 2 : 1;
  for (int ph = 0; ph < nph; ph++) {
    if (ph) __syncthreads();
    const u16* A = (DUAL && ph) ? A2 : A1;
    const u16* WT = (DUAL && ph) ? WT2 : WT1;
    // ---- stage A: 2048 16B-chunks; global read fully coalesced; padded LDS ----
    #pragma unroll
    for (int i = 0; i < 8; i++) {
      int c = i*256 + t; int row = c >> 4; int k0 = (c & 15) << 3;
      uint4 w = {0,0,0,0};
      if (row0 + row < M)
        w = *reinterpret_cast<const uint4*>(A + (size_t)(row0+row)*128 + k0);
      if constexpr (BNA) {
        float4 sc0 = *reinterpret_cast<const float4*>(&s_scale[k0]);
        float4 sc1 = *reinterpret_cast<const float4*>(&s_scale[k0+4]);
        float4 sh0 = *reinterpret_cast<const float4*>(&s_shift[k0]);
        float4 sh1 = *reinterpret_cast<const float4*>(&s_shift[k0+4]);
        float e0 = fmaxf(bl(w.x)*sc0.x+sh0.x, 0.f), e1 = fmaxf(bh(w.x)*sc0.y+sh0.y, 0.f);
        float e2 = fmaxf(bl(w.y)*sc0.z+sh0.z, 0.f), e3 = fmaxf(bh(w.y)*sc0.w+sh0.w, 0.f);
        float e4 = fmaxf(bl(w.z)*sc1.x+sh1.x, 0.f), e5 = fmaxf(bh(w.z)*sc1.y+sh1.y, 0.f);
        float e6 = fmaxf(bl(w.w)*sc1.z+sh1.z, 0.f), e7 = fmaxf(bh(w.w)*sc1.w+sh1.w, 0.f);
        w.x = f2bf(e0) | (f2bf(e1)<<16);
        w.y = f2bf(e2) | (f2bf(e3)<<16);
        w.z = f2bf(e4) | (f2bf(e5)<<16);
        w.w = f2bf(e6) | (f2bf(e7)<<16);
      }
      *reinterpret_cast<uint4*>(ldsA + row*272 + k0*2) = w;
    }
    // ---- stage W: linear copy of fragment-order global (conflict-free) ----
    #pragma unroll
    for (int i = 0; i < NCOLS/16; i++) {
      int c = i*256 + t;
      reinterpret_cast<uint4*>(ldsW)[c] = reinterpret_cast<const uint4*>(WT)[c];
    }
    __syncthreads();
    // ---- compute: 8 k-steps ----
    #pragma unroll
    for (int ks = 0; ks < 8; ks++) {
      int kc = ks*2 + h;                       // 16B chunk index
      int arow = wave*32 + lm;
      short8v af = *reinterpret_cast<short8v*>(ldsA + arow*272 + kc*16);
      #pragma unroll
      for (int nf = 0; nf < NF; nf++) {
        short8v bf = *reinterpret_cast<short8v*>(ldsW + ((kc*NF + nf)*32 + lm)*16);
        acc[nf] = __builtin_amdgcn_mfma_f32_32x32x16_bf16(af, bf, acc[nf], 0, 0, 0);
      }
    }
  }
  // ---- epilogue ----
  if constexpr (HEAD) {
    __syncthreads();                           // A reads done; reuse ldsA for m1
    float* mrow = reinterpret_cast<float*>(ldsA);  // [128][65]
    #pragma unroll
    for (int nf = 0; nf < NF; nf++) {
      int colg = nf*32 + lm;
      float bv = bias[colg];
      #pragma unroll
      for (int reg = 0; reg < 16; reg++) {
        int row = wave*32 + (reg&3) + 8*(reg>>2) + 4*h;
        mrow[row*65 + colg] = fmaxf(acc[nf][reg] + bv, 0.f);
      }
    }
    __syncthreads();
    if (t < 128) {
      int row = row0 + t;
      if (row < M) {
        float p[OC];
        #pragma unroll
        for (int c = 0; c < OC; c++) p[c] = b2s[c];
        for (int k = 0; k < Hh; k++) {
          float a = mrow[t*65 + k];
          #pragma unroll
          for (int c = 0; c < OC; c++) p[c] += a * w2s[k][c];
        }
        float mx = p[0];
        #pragma unroll
        for (int c = 1; c < OC; c++) mx = fmaxf(mx, p[c]);
        float s = 0.f;
        #pragma unroll
        for (int c = 0; c < OC; c++) s += __expf(p[c] - mx);
        float lse = mx + __logf(s);
        #pragma unroll
        for (int c = 0; c < OC; c++)
          ((float*)Cout)[(size_t)row*OC + c] = p[c] - lse;
      }
    }
    return;
  }
  #pragma unroll
  for (int nf = 0; nf < NF; nf++) {
    int colg = nf*32 + lm;
    float bv = 0.f;
    if constexpr (BIASRELU) bv = bias[colg];
    float ps = 0.f, pq = 0.f;
    #pragma unroll
    for (int reg = 0; reg < 16; reg++) {
      int row = row0 + wave*32 + (reg&3) + 8*(reg>>2) + 4*h;
      float v = acc[nf][reg];
      if constexpr (BIASRELU) v = fmaxf(v + bv, 0.f);
      if (row < M) {
        if constexpr (OUTBF)
          ((u16*)Cout)[(size_t)row*NCOLS + colg] = (u16)f2bf(v);
        else
          ((float*)Cout)[(size_t)row*NCOLS + colg] = v;
      }
      ps += v; pq += v*v;
    }
    if constexpr (STATS) {
      atomicAdd(&s_sum[colg], ps);
      atomicAdd(&s_sq[colg], pq);
    }
  }
  if constexpr (ATT) {
    float as_c[NF], ad_c[NF];
    #pragma unroll
    for (int nf = 0; nf < NF; nf++) { as_c[nf] = att_sv[nf*32+lm]; ad_c[nf] = att_dv[nf*32+lm]; }
    #pragma unroll
    for (int reg = 0; reg < 16; reg++) {
      float ps = 0.f, pd = 0.f;
      #pragma unroll
      for (int nf = 0; nf < NF; nf++) { float v = acc[nf][reg]; ps += v*as_c[nf]; pd += v*ad_c[nf]; }
      #pragma unroll
      for (int mm = 1; mm < 32; mm <<= 1) { ps += __shfl_xor(ps, mm); pd += __shfl_xor(pd, mm); }
      int row = row0 + wave*32 + (reg&3) + 8*(reg>>2) + 4*h;
      if (lm == 0 && row < M) { as_out[row] = ps; ad_out[row] = pd; }
    }
  }
  if constexpr (STATS) {
    __syncthreads();
    if (t < 128) { atomicAdd(gsum + t, s_sum[t]); atomicAdd(gsq + t, s_sq[t]); }
  }
}

// ======================= launch =======================
extern "C" void kernel_launch(void* const* d_in, const int* in_sizes, int n_in,
                              void* d_out, int out_size, void* d_ws, size_t ws_size,
                              hipStream_t stream) {
  const float* x       = (const float*)d_in[0];
  const int*   ei      = (const int*)d_in[1];
  const float* sage_Wl = (const float*)d_in[2];
  const float* sage_Wr = (const float*)d_in[3];
  const float* gcn_W   = (const float*)d_in[5];
  const float* gat_W   = (const float*)d_in[7];
  const float* att_s   = (const float*)d_in[8];
  const float* att_d   = (const float*)d_in[9];
  const float* bn1_g = (const float*)d_in[11], *bn1_b = (const float*)d_in[12];
  const float* bn2_g = (const float*)d_in[13], *bn2_b = (const float*)d_in[14];
  const float* bn3_g = (const float*)d_in[15], *bn3_b = (const float*)d_in[16];
  const float* lin1_W = (const float*)d_in[17], *lin1_b = (const float*)d_in[18];
  const float* lin2_W = (const float*)d_in[19], *lin2_b = (const float*)d_in[20];

  const int Nn = in_sizes[0] / Dd;     // 100000
  const int Ee = in_sizes[1] / 2;      // 600000
  const int* srcv = ei;
  const int* dstv = ei + Ee;

  u16* b0 = (u16*)d_ws;                        // N*128 bf16 each
  u16* b1 = b0 + (size_t)Nn*Dd;
  u16* b2 = b1 + (size_t)Nn*Dd;
  float* dinv  = (float*)(b2 + (size_t)Nn*Dd); // N
  float* a_s   = dinv + Nn;                    // N
  float* a_d   = a_s + Nn;                     // N
  float* bs    = a_d + Nn;                     // 6*128
  float* bs1_sum = bs,        *bs1_sq = bs + 128;
  float* bs2_sum = bs + 256,  *bs2_sq = bs + 384;
  float* bs3_sum = bs + 512,  *bs3_sq = bs + 640;
  int* rp    = (int*)(bs + 768);               // N+1
  int* cnt_i = rp + (Nn + 1);                  // N
  int* bsum  = cnt_i + Nn;                     // 64
  int* col   = bsum + 64;                      // E
  u16* wt_sWl = (u16*)(col + Ee);              // 128*128 each (frag order)
  u16* wt_sWr = wt_sWl + 128*128;
  u16* wt_gcn = wt_sWr + 128*128;
  u16* wt_gat = wt_gcn + 128*128;
  u16* wt_l1  = wt_gat + 128*128;              // 128*64

  const dim3 B(256);
  const dim3 Gn(CDIV(Nn, 256));
  const dim3 Gn32(CDIV(Nn*32, 256));
  const dim3 Ge(CDIV(Ee, 256));
  const dim3 Gmm(CDIV(Nn, 128));
  const dim3 Gstat(512);
  const int nscan = CDIV(Nn, 2048);

  // ---------- zeroing (once) ----------
  hipMemsetAsync(cnt_i, 0, (size_t)Nn*sizeof(int), stream);
  hipMemsetAsync(bs, 0, 768*sizeof(float), stream);

  // ---------- CSR + weight prep + x->bf16 ----------
  k_hist<<<Ge, B, 0, stream>>>(dstv, Ee, cnt_i);
  k_scan_l1<<<dim3(nscan), B, 0, stream>>>(cnt_i, rp, Nn, bsum);
  k_scan_l2<<<dim3(1), dim3(64), 0, stream>>>(bsum, nscan);
  k_scan_l3<<<dim3(nscan), B, 0, stream>>>(rp, Nn, bsum, Ee);
  k_fill<<<Ge, B, 0, stream>>>(srcv, dstv, Ee, rp, cnt_i, col);
  k_dinv<<<Gn, B, 0, stream>>>(rp, dinv, Nn);
  k_wt_all<<<dim3(288), B, 0, stream>>>(sage_Wl, sage_Wr, gcn_W, gat_W, lin1_W,
                                        wt_sWl, wt_sWr, wt_gcn, wt_gat, wt_l1);
  k_tobf16<<<dim3(CDIV(Nn*Dd/8, 256)), B, 0, stream>>>(x, b0, Nn*Dd/8);

  // ---------- Layer 1: SAGE ----------
  k_sage_gather<<<Gn32, B, 0, stream>>>(b0, rp, col, b1, Nn);   // mean -> b1
  k_mm<128, true, false, true, false, false, true, false><<<Gmm, B, 0, stream>>>(
      b1, b0, wt_sWl, wt_sWr, nullptr, nullptr, nullptr, nullptr, nullptr,
      b2, Nn, bs1_sum, bs1_sq, nullptr, nullptr, nullptr, nullptr, nullptr, nullptr);

  // ---------- Layer 2: GCN ----------
  k_mm<128, false, true, false, false, false, true, false><<<Gmm, B, 0, stream>>>(
      b2, nullptr, wt_gcn, nullptr, bn1_g, bn1_b, bs1_sum, bs1_sq, nullptr,
      b0, Nn, nullptr, nullptr, nullptr, nullptr, nullptr, nullptr, nullptr, nullptr);
  k_gcn_gather<<<Gn32, B, 0, stream>>>(b0, rp, col, dinv, b1, Nn);  // pre2 -> b1
  k_bn_stats_bf<<<Gstat, B, 0, stream>>>(b1, Nn, bs2_sum, bs2_sq);

  // ---------- Layer 3: GAT ----------
  k_mm<128, false, true, false, false, true, true, false><<<Gmm, B, 0, stream>>>(
      b1, nullptr, wt_gat, nullptr, bn2_g, bn2_b, bs2_sum, bs2_sq, nullptr,
      b2, Nn, nullptr, nullptr, att_s, att_d, a_s, a_d, nullptr, nullptr);
  k_gat_gather<<<Gn32, B, 0, stream>>>(b2, rp, col, a_s, a_d, b0, Nn);  // pre3 -> b0
  k_bn_stats_bf<<<Gstat, B, 0, stream>>>(b0, Nn, bs3_sum, bs3_sq);

  // ---------- MLP head (lin1 + lin2 + log_softmax fused) ----------
  k_mm<64, false, true, false, true, false, false, true><<<Gmm, B, 0, stream>>>(
      b0, nullptr, wt_l1, nullptr, bn3_g, bn3_b, bs3_sum, bs3_sq, lin1_b,
      (float*)d_out, Nn, nullptr, nullptr, nullptr, nullptr, nullptr, nullptr,
      lin2_W, lin2_b);
}